// Round 2
// baseline (213.509 us; speedup 1.0000x reference)
//
#include <hip/hip_runtime.h>

#define C_CH 128
#define H_IN 80
#define W_IN 80
#define HW 6400
#define OUTS 7
#define NBINS 49   // 7x7

// ---------------- transpose (B,C,H,W) -> (B,H,W,C) ----------------
__global__ __launch_bounds__(256) void transpose_kernel(const float* __restrict__ in,
                                                        float* __restrict__ out) {
    __shared__ float tile[32][33];
    const int b  = blockIdx.z;
    const int c0 = blockIdx.y * 32;   // channel tile
    const int s0 = blockIdx.x * 32;   // spatial (h*W+w) tile
    const int tx = threadIdx.x, ty = threadIdx.y;  // block (32,8)
#pragma unroll
    for (int i = 0; i < 32; i += 8)
        tile[ty + i][tx] = in[(size_t)(b * C_CH + c0 + ty + i) * HW + s0 + tx];
    __syncthreads();
#pragma unroll
    for (int i = 0; i < 32; i += 8)
        out[(size_t)(b * HW + s0 + ty + i) * C_CH + c0 + tx] = tile[tx][ty + i];
}

// ---------------- main deformable RoI pool (transposed data) ----------------
// Block = (n, ph), 256 threads = 4 waves. Wave w handles pw = w, w+4.
// Lane l owns channels 2l, 2l+1 (float2 gather from NHWC data).
// Validity is separable: valid(ih,iw) = hv[ih] & wv[iw]; fold into lerp
// weights d0/d1 (rows) and c0/c1 (cols); cnt = nh*nw. Fully unrolled 4x4
// sampling -> 64 independent dwordx2 loads per bin.
__global__ __launch_bounds__(256, 6) void droi_kernel2(const float2* __restrict__ d2,
                                                       const float* __restrict__ rois,
                                                       const float* __restrict__ offset,
                                                       float* __restrict__ out) {
    __shared__ float lds[C_CH * OUTS];
    const int n    = blockIdx.x;
    const int ph   = blockIdx.y;
    const int tid  = threadIdx.x;
    const int wave = tid >> 6;
    const int lane = tid & 63;

    const int   b     = (int)rois[n * 5 + 0];
    const float sw    = rintf(rois[n * 5 + 1]) * 0.0625f - 0.5f;
    const float sh    = rintf(rois[n * 5 + 2]) * 0.0625f - 0.5f;
    const float ew    = (rintf(rois[n * 5 + 3]) + 1.0f) * 0.0625f - 0.5f;
    const float eh    = (rintf(rois[n * 5 + 4]) + 1.0f) * 0.0625f - 0.5f;
    const float roi_w = fmaxf(ew - sw, 0.1f);
    const float roi_h = fmaxf(eh - sh, 0.1f);
    const float bin_w = roi_w / 7.0f;
    const float bin_h = roi_h / 7.0f;
    const float sub_w = bin_w / 4.0f;
    const float sub_h = bin_h / 4.0f;
    const int   pixbase = b * HW;

    for (int pw = wave; pw < OUTS; pw += 4) {
        float hs[4], wsm[4];
        {
#pragma clang fp contract(off)
            // PART_SIZE == OUT_SIZE == 7 -> part_h == ph, part_w == pw.
            const float tx = offset[(n * 2 + 0) * NBINS + ph * OUTS + pw] * 0.1f;
            const float ty = offset[(n * 2 + 1) * NBINS + ph * OUTS + pw] * 0.1f;
            const float wstart = (float)pw * bin_w + sw + tx * roi_w;
            const float hstart = (float)ph * bin_h + sh + ty * roi_h;
#pragma unroll
            for (int i = 0; i < 4; i++) {
                hs[i]  = hstart + (float)i * sub_h;
                wsm[i] = wstart + (float)i * sub_w;
            }
        }

        int   rA[4], rB[4];
        float d0[4], d1[4];
        int   nh = 0;
#pragma unroll
        for (int i = 0; i < 4; i++) {
            const float h  = hs[i];
            const int   hv = (h >= -0.5f) && (h <= (float)H_IN - 0.5f);
            nh += hv;
            const float hc = fminf(fmaxf(h, 0.0f), (float)H_IN - 1.0f);
            const int   h0 = (int)hc;                  // hc >= 0 -> trunc == floor
            const int   h1 = min(h0 + 1, H_IN - 1);
            const float lh = hc - (float)h0;
            const float f  = hv ? 1.0f : 0.0f;
            d0[i] = (1.0f - lh) * f;
            d1[i] = lh * f;
            rA[i] = (pixbase + h0 * W_IN) * (C_CH / 2) + lane;
            rB[i] = (pixbase + h1 * W_IN) * (C_CH / 2) + lane;
        }

        int   cA[4], cB[4];
        float c0[4], c1[4];
        int   nw = 0;
#pragma unroll
        for (int i = 0; i < 4; i++) {
            const float w  = wsm[i];
            const int   wv = (w >= -0.5f) && (w <= (float)W_IN - 0.5f);
            nw += wv;
            const float wc = fminf(fmaxf(w, 0.0f), (float)W_IN - 1.0f);
            const int   w0 = (int)wc;
            const int   w1 = min(w0 + 1, W_IN - 1);
            const float lw = wc - (float)w0;
            const float f  = wv ? 1.0f : 0.0f;
            c0[i] = (1.0f - lw) * f;
            c1[i] = lw * f;
            cA[i] = w0 * (C_CH / 2);
            cB[i] = w1 * (C_CH / 2);
        }

        float ax = 0.0f, ay = 0.0f;
#pragma unroll
        for (int ih = 0; ih < 4; ih++) {
#pragma unroll
            for (int iw = 0; iw < 4; iw++) {
                const float2 v00 = d2[rA[ih] + cA[iw]];
                const float2 v01 = d2[rA[ih] + cB[iw]];
                const float2 v10 = d2[rB[ih] + cA[iw]];
                const float2 v11 = d2[rB[ih] + cB[iw]];
                const float tx0 = c0[iw] * v00.x + c1[iw] * v01.x;
                const float ty0 = c0[iw] * v00.y + c1[iw] * v01.y;
                const float bx0 = c0[iw] * v10.x + c1[iw] * v11.x;
                const float by0 = c0[iw] * v10.y + c1[iw] * v11.y;
                ax += d0[ih] * tx0 + d1[ih] * bx0;
                ay += d0[ih] * ty0 + d1[ih] * by0;
            }
        }
        const int   cnt = nh * nw;
        const float inv = cnt > 0 ? 1.0f / (float)cnt : 0.0f;
        lds[(2 * lane) * OUTS + pw]     = ax * inv;
        lds[(2 * lane + 1) * OUTS + pw] = ay * inv;
    }
    __syncthreads();
    // out[n, c, ph, pw]: 896 floats per block.
    const size_t obase = (size_t)n * (C_CH * NBINS) + (size_t)ph * OUTS;
    for (int f = tid; f < C_CH * OUTS; f += 256) {
        const int c = f / OUTS, k = f - c * OUTS;
        out[obase + (size_t)c * NBINS + k] = lds[f];
    }
}

// ---------------- fallback (no workspace): original CHW gather ----------------
__global__ __launch_bounds__(512) void droi_fallback(const float* __restrict__ data,
                                                     const float* __restrict__ rois,
                                                     const float* __restrict__ offset,
                                                     float* __restrict__ out) {
#pragma clang fp contract(off)
    __shared__ float lds[C_CH * NBINS];
    const int n    = blockIdx.x;
    const int tid  = threadIdx.x;
    const int wave = tid >> 6;
    const int lane = tid & 63;

    const int   b     = (int)rois[n * 5 + 0];
    const float sw    = rintf(rois[n * 5 + 1]) * 0.0625f - 0.5f;
    const float sh    = rintf(rois[n * 5 + 2]) * 0.0625f - 0.5f;
    const float ew    = (rintf(rois[n * 5 + 3]) + 1.0f) * 0.0625f - 0.5f;
    const float eh    = (rintf(rois[n * 5 + 4]) + 1.0f) * 0.0625f - 0.5f;
    const float roi_w = fmaxf(ew - sw, 0.1f);
    const float roi_h = fmaxf(eh - sh, 0.1f);
    const float bin_w = roi_w / 7.0f, bin_h = roi_h / 7.0f;
    const float sub_w = bin_w / 4.0f, sub_h = bin_h / 4.0f;

    for (int bin = wave; bin < NBINS; bin += 8) {
        const int ph = bin / 7;
        const int pw = bin - ph * 7;
        const float tx = offset[((n * 2 + 0) * 7 + ph) * 7 + pw] * 0.1f;
        const float ty = offset[((n * 2 + 1) * 7 + ph) * 7 + pw] * 0.1f;
        const float wstart = (float)pw * bin_w + sw + tx * roi_w;
        const float hstart = (float)ph * bin_h + sh + ty * roi_h;
        float s0 = 0.0f, s1 = 0.0f;
        int   cnt = 0;
        for (int ih = 0; ih < 4; ih++) {
            const float h = hstart + (float)ih * sub_h;
            if (h < -0.5f || h > (float)H_IN - 0.5f) continue;
            for (int iw = 0; iw < 4; iw++) {
                const float w = wstart + (float)iw * sub_w;
                if (w < -0.5f || w > (float)W_IN - 0.5f) continue;
                cnt++;
                const float hc = fminf(fmaxf(h, 0.0f), (float)H_IN - 1.0f);
                const float wc = fminf(fmaxf(w, 0.0f), (float)W_IN - 1.0f);
                const int h0 = (int)floorf(hc), w0 = (int)floorf(wc);
                const int h1 = min(h0 + 1, H_IN - 1), w1 = min(w0 + 1, W_IN - 1);
                const float lh = hc - (float)h0, lw = wc - (float)w0;
                const float w00 = (1.0f - lh) * (1.0f - lw), w01 = (1.0f - lh) * lw;
                const float w10 = lh * (1.0f - lw), w11 = lh * lw;
                const float* pb  = data + (size_t)b * C_CH * HW;
                const int i00 = h0 * W_IN + w0, i01 = h0 * W_IN + w1;
                const int i10 = h1 * W_IN + w0, i11 = h1 * W_IN + w1;
                const float* pc0 = pb + (size_t)lane * HW;
                const float* pc1 = pb + (size_t)(lane + 64) * HW;
                s0 += w00 * pc0[i00] + w01 * pc0[i01] + w10 * pc0[i10] + w11 * pc0[i11];
                s1 += w00 * pc1[i00] + w01 * pc1[i01] + w10 * pc1[i10] + w11 * pc1[i11];
            }
        }
        lds[lane * NBINS + bin]        = cnt > 0 ? s0 / (float)cnt : 0.0f;
        lds[(lane + 64) * NBINS + bin] = cnt > 0 ? s1 / (float)cnt : 0.0f;
    }
    __syncthreads();
    const size_t obase = (size_t)n * (C_CH * NBINS);
    for (int f = tid; f < C_CH * NBINS; f += 512)
        out[obase + f] = lds[f];
}

extern "C" void kernel_launch(void* const* d_in, const int* in_sizes, int n_in,
                              void* d_out, int out_size, void* d_ws, size_t ws_size,
                              hipStream_t stream) {
    const float* data   = (const float*)d_in[0];
    const float* rois   = (const float*)d_in[1];
    const float* offset = (const float*)d_in[2];
    float*       outp   = (float*)d_out;

    const int N = in_sizes[1] / 5;                 // 512
    const int B = in_sizes[0] / (C_CH * HW);       // 2
    const size_t need = (size_t)B * HW * C_CH * sizeof(float);

    if (ws_size >= need) {
        dim3 gt(HW / 32, C_CH / 32, B), bt(32, 8);
        transpose_kernel<<<gt, bt, 0, stream>>>(data, (float*)d_ws);
        dim3 gd(N, OUTS);
        droi_kernel2<<<gd, 256, 0, stream>>>((const float2*)d_ws, rois, offset, outp);
    } else {
        droi_fallback<<<N, 512, 0, stream>>>(data, rois, offset, outp);
    }
}

// Round 3
// 70.702 us; speedup vs baseline: 3.0198x; 3.0198x over previous
//
#include <hip/hip_runtime.h>

#define C_CH 128
#define H_IN 80
#define W_IN 80
#define HW 6400
#define OUTS 7
#define NBINS 49   // 7x7

// ---------------- transpose (B,C,H,W) -> (B,H,W,C) ----------------
__global__ __launch_bounds__(256) void transpose_kernel(const float* __restrict__ in,
                                                        float* __restrict__ out) {
    __shared__ float tile[32][33];
    const int b  = blockIdx.z;
    const int c0 = blockIdx.y * 32;   // channel tile
    const int s0 = blockIdx.x * 32;   // spatial (h*W+w) tile
    const int tx = threadIdx.x, ty = threadIdx.y;  // block (32,8)
#pragma unroll
    for (int i = 0; i < 32; i += 8)
        tile[ty + i][tx] = in[(size_t)(b * C_CH + c0 + ty + i) * HW + s0 + tx];
    __syncthreads();
#pragma unroll
    for (int i = 0; i < 32; i += 8)
        out[(size_t)(b * HW + s0 + ty + i) * C_CH + c0 + tx] = tile[tx][ty + i];
}

// ---------------- main deformable RoI pool (NHWC data) ----------------
// Grid (N, 7), block 448 = 7 waves. Wave == pw: exactly ONE bin per wave,
// no bin loop. Lane l owns channels 2l, 2l+1 (float2 gather).
// All row/col bilinear factors are NAMED SCALARS (macro-expanded) -- R2's
// local arrays were demoted to scratch (570 MB HBM writes); this forbids it.
// Validity separable: weight rows/cols by hv/wv flags; cnt = nh*nw.

#define MKROW(i)                                                              \
    float d0_##i, d1_##i; int rA_##i, rB_##i;                                 \
    {                                                                         \
        const float h  = h_##i;                                              \
        const int   hv = (h >= -0.5f) && (h <= (float)H_IN - 0.5f);          \
        nh += hv;                                                            \
        const float hc = fminf(fmaxf(h, 0.0f), (float)H_IN - 1.0f);          \
        const int   h0 = (int)hc;  /* hc >= 0 -> trunc == floor */           \
        const int   h1 = min(h0 + 1, H_IN - 1);                              \
        const float lh = hc - (float)h0;                                     \
        const float f  = hv ? 1.0f : 0.0f;                                   \
        d0_##i = (1.0f - lh) * f;                                            \
        d1_##i = lh * f;                                                     \
        rA_##i = (pixbase + h0 * W_IN) * (C_CH / 2) + lane;                  \
        rB_##i = (pixbase + h1 * W_IN) * (C_CH / 2) + lane;                  \
    }

#define MKCOL(j)                                                              \
    float c0_##j, c1_##j; int cA_##j, cB_##j;                                 \
    {                                                                         \
        const float w  = w_##j;                                              \
        const int   wv = (w >= -0.5f) && (w <= (float)W_IN - 0.5f);          \
        nw += wv;                                                            \
        const float wc = fminf(fmaxf(w, 0.0f), (float)W_IN - 1.0f);          \
        const int   w0 = (int)wc;                                            \
        const int   w1 = min(w0 + 1, W_IN - 1);                              \
        const float lw = wc - (float)w0;                                     \
        const float f  = wv ? 1.0f : 0.0f;                                   \
        c0_##j = (1.0f - lw) * f;                                            \
        c1_##j = lw * f;                                                     \
        cA_##j = w0 * (C_CH / 2);                                            \
        cB_##j = w1 * (C_CH / 2);                                            \
    }

#define SAMP(i, j)                                                            \
    {                                                                         \
        const float2 v00 = d2[rA_##i + cA_##j];                              \
        const float2 v01 = d2[rA_##i + cB_##j];                              \
        const float2 v10 = d2[rB_##i + cA_##j];                              \
        const float2 v11 = d2[rB_##i + cB_##j];                              \
        ax += d0_##i * (c0_##j * v00.x + c1_##j * v01.x) +                   \
              d1_##i * (c0_##j * v10.x + c1_##j * v11.x);                    \
        ay += d0_##i * (c0_##j * v00.y + c1_##j * v01.y) +                   \
              d1_##i * (c0_##j * v10.y + c1_##j * v11.y);                    \
    }

__global__ __launch_bounds__(448) void droi_kernel3(const float2* __restrict__ d2,
                                                    const float* __restrict__ rois,
                                                    const float* __restrict__ offset,
                                                    float* __restrict__ out) {
    const int n    = blockIdx.x;
    const int ph   = blockIdx.y;
    const int pw   = threadIdx.x >> 6;   // wave id == output column
    const int lane = threadIdx.x & 63;

    const int b       = (int)rois[n * 5 + 0];
    const int pixbase = b * HW;

    float h_0, h_1, h_2, h_3, w_0, w_1, w_2, w_3;
    {
#pragma clang fp contract(off)
        const float sw    = rintf(rois[n * 5 + 1]) * 0.0625f - 0.5f;
        const float sh    = rintf(rois[n * 5 + 2]) * 0.0625f - 0.5f;
        const float ew    = (rintf(rois[n * 5 + 3]) + 1.0f) * 0.0625f - 0.5f;
        const float eh    = (rintf(rois[n * 5 + 4]) + 1.0f) * 0.0625f - 0.5f;
        const float roi_w = fmaxf(ew - sw, 0.1f);
        const float roi_h = fmaxf(eh - sh, 0.1f);
        const float bin_w = roi_w / 7.0f;
        const float bin_h = roi_h / 7.0f;
        const float sub_w = bin_w / 4.0f;
        const float sub_h = bin_h / 4.0f;
        // PART_SIZE == OUT_SIZE == 7 -> part_h == ph, part_w == pw.
        const float tx = offset[(n * 2 + 0) * NBINS + ph * OUTS + pw] * 0.1f;
        const float ty = offset[(n * 2 + 1) * NBINS + ph * OUTS + pw] * 0.1f;
        const float wstart = (float)pw * bin_w + sw + tx * roi_w;
        const float hstart = (float)ph * bin_h + sh + ty * roi_h;
        h_0 = hstart;                 w_0 = wstart;
        h_1 = hstart + sub_h;         w_1 = wstart + sub_w;
        h_2 = hstart + 2.0f * sub_h;  w_2 = wstart + 2.0f * sub_w;
        h_3 = hstart + 3.0f * sub_h;  w_3 = wstart + 3.0f * sub_w;
    }

    int nh = 0, nw = 0;
    MKROW(0) MKROW(1) MKROW(2) MKROW(3)
    MKCOL(0) MKCOL(1) MKCOL(2) MKCOL(3)

    float ax = 0.0f, ay = 0.0f;
    SAMP(0, 0) SAMP(0, 1) SAMP(0, 2) SAMP(0, 3)
    SAMP(1, 0) SAMP(1, 1) SAMP(1, 2) SAMP(1, 3)
    SAMP(2, 0) SAMP(2, 1) SAMP(2, 2) SAMP(2, 3)
    SAMP(3, 0) SAMP(3, 1) SAMP(3, 2) SAMP(3, 3)

    const int   cnt = nh * nw;
    const float inv = cnt > 0 ? 1.0f / (float)cnt : 0.0f;
    // out[n, c, ph, pw]
    const size_t base = (size_t)n * (C_CH * NBINS) + (size_t)ph * OUTS + pw;
    out[base + (size_t)(2 * lane) * NBINS]     = ax * inv;
    out[base + (size_t)(2 * lane + 1) * NBINS] = ay * inv;
}

// ---------------- fallback (no workspace): CHW gather, known-correct ---------
__global__ __launch_bounds__(512) void droi_fallback(const float* __restrict__ data,
                                                     const float* __restrict__ rois,
                                                     const float* __restrict__ offset,
                                                     float* __restrict__ out) {
#pragma clang fp contract(off)
    __shared__ float lds[C_CH * NBINS];
    const int n    = blockIdx.x;
    const int tid  = threadIdx.x;
    const int wave = tid >> 6;
    const int lane = tid & 63;

    const int   b     = (int)rois[n * 5 + 0];
    const float sw    = rintf(rois[n * 5 + 1]) * 0.0625f - 0.5f;
    const float sh    = rintf(rois[n * 5 + 2]) * 0.0625f - 0.5f;
    const float ew    = (rintf(rois[n * 5 + 3]) + 1.0f) * 0.0625f - 0.5f;
    const float eh    = (rintf(rois[n * 5 + 4]) + 1.0f) * 0.0625f - 0.5f;
    const float roi_w = fmaxf(ew - sw, 0.1f);
    const float roi_h = fmaxf(eh - sh, 0.1f);
    const float bin_w = roi_w / 7.0f, bin_h = roi_h / 7.0f;
    const float sub_w = bin_w / 4.0f, sub_h = bin_h / 4.0f;

    for (int bin = wave; bin < NBINS; bin += 8) {
        const int ph = bin / 7;
        const int pw = bin - ph * 7;
        const float tx = offset[((n * 2 + 0) * 7 + ph) * 7 + pw] * 0.1f;
        const float ty = offset[((n * 2 + 1) * 7 + ph) * 7 + pw] * 0.1f;
        const float wstart = (float)pw * bin_w + sw + tx * roi_w;
        const float hstart = (float)ph * bin_h + sh + ty * roi_h;
        float s0 = 0.0f, s1 = 0.0f;
        int   cnt = 0;
        for (int ih = 0; ih < 4; ih++) {
            const float h = hstart + (float)ih * sub_h;
            if (h < -0.5f || h > (float)H_IN - 0.5f) continue;
            for (int iw = 0; iw < 4; iw++) {
                const float w = wstart + (float)iw * sub_w;
                if (w < -0.5f || w > (float)W_IN - 0.5f) continue;
                cnt++;
                const float hc = fminf(fmaxf(h, 0.0f), (float)H_IN - 1.0f);
                const float wc = fminf(fmaxf(w, 0.0f), (float)W_IN - 1.0f);
                const int h0 = (int)floorf(hc), w0 = (int)floorf(wc);
                const int h1 = min(h0 + 1, H_IN - 1), w1 = min(w0 + 1, W_IN - 1);
                const float lh = hc - (float)h0, lw = wc - (float)w0;
                const float w00 = (1.0f - lh) * (1.0f - lw), w01 = (1.0f - lh) * lw;
                const float w10 = lh * (1.0f - lw), w11 = lh * lw;
                const float* pb  = data + (size_t)b * C_CH * HW;
                const int i00 = h0 * W_IN + w0, i01 = h0 * W_IN + w1;
                const int i10 = h1 * W_IN + w0, i11 = h1 * W_IN + w1;
                const float* pc0 = pb + (size_t)lane * HW;
                const float* pc1 = pb + (size_t)(lane + 64) * HW;
                s0 += w00 * pc0[i00] + w01 * pc0[i01] + w10 * pc0[i10] + w11 * pc0[i11];
                s1 += w00 * pc1[i00] + w01 * pc1[i01] + w10 * pc1[i10] + w11 * pc1[i11];
            }
        }
        lds[lane * NBINS + bin]        = cnt > 0 ? s0 / (float)cnt : 0.0f;
        lds[(lane + 64) * NBINS + bin] = cnt > 0 ? s1 / (float)cnt : 0.0f;
    }
    __syncthreads();
    const size_t obase = (size_t)n * (C_CH * NBINS);
    for (int f = tid; f < C_CH * NBINS; f += 512)
        out[obase + f] = lds[f];
}

extern "C" void kernel_launch(void* const* d_in, const int* in_sizes, int n_in,
                              void* d_out, int out_size, void* d_ws, size_t ws_size,
                              hipStream_t stream) {
    const float* data   = (const float*)d_in[0];
    const float* rois   = (const float*)d_in[1];
    const float* offset = (const float*)d_in[2];
    float*       outp   = (float*)d_out;

    const int N = in_sizes[1] / 5;                 // 512
    const int B = in_sizes[0] / (C_CH * HW);       // 2
    const size_t need = (size_t)B * HW * C_CH * sizeof(float);

    if (ws_size >= need) {
        dim3 gt(HW / 32, C_CH / 32, B), bt(32, 8);
        transpose_kernel<<<gt, bt, 0, stream>>>(data, (float*)d_ws);
        dim3 gd(N, OUTS);
        droi_kernel3<<<gd, 448, 0, stream>>>((const float2*)d_ws, rois, offset, outp);
    } else {
        droi_fallback<<<N, 512, 0, stream>>>(data, rois, offset, outp);
    }
}

// Round 4
// 39.408 us; speedup vs baseline: 5.4178x; 1.7941x over previous
//
#include <hip/hip_runtime.h>

#define C_CH 128
#define H_IN 80
#define W_IN 80
#define HW 6400
#define OUTS 7
#define NBINS 49   // 7x7

// ---------------- transpose (B,C,H,W) -> (B,H,W,C) ----------------
__global__ __launch_bounds__(256) void transpose_kernel(const float* __restrict__ in,
                                                        float* __restrict__ out) {
    __shared__ float tile[32][33];
    const int b  = blockIdx.z;
    const int c0 = blockIdx.y * 32;   // channel tile
    const int s0 = blockIdx.x * 32;   // spatial (h*W+w) tile
    const int tx = threadIdx.x, ty = threadIdx.y;  // block (32,8)
#pragma unroll
    for (int i = 0; i < 32; i += 8)
        tile[ty + i][tx] = in[(size_t)(b * C_CH + c0 + ty + i) * HW + s0 + tx];
    __syncthreads();
#pragma unroll
    for (int i = 0; i < 32; i += 8)
        out[(size_t)(b * HW + s0 + ty + i) * C_CH + c0 + tx] = tile[tx][ty + i];
}

// ---------------- main deformable RoI pool (NHWC, rank-1 window gather) -----
// Grid (N, 7), block 448 = 7 waves, wave == pw (one bin per wave).
// The 4x4 subsamples' 64 bilinear corners hit <= 6x6 DISTINCT pixels, and the
// total weight matrix is rank-1: W(r,c) = R_r * C_c with
//   R_r = sum_i d0_i*[slot_i==r] + d1_i*[slot_i==r-1]   (slots rel. to rbase)
// (clamped h0==79 => lh==0 => d1==0, so "slot+1" is always safe; invalid
// samples have weight 0 folded in; cnt = nh*nw as before).
// Gather: 6x6 window, whole rows skipped when R_r==0 (wave-uniform branch).
// All weights are NAMED SCALARS (macros) -- no local arrays -> no scratch.

#define MKR(i)                                                                \
    {                                                                         \
        const float h  = h_##i;                                              \
        const int   hv = (h >= -0.5f) && (h <= (float)H_IN - 0.5f);          \
        nh += hv;                                                            \
        const float hc = fminf(fmaxf(h, 0.0f), (float)H_IN - 1.0f);          \
        const int   h0 = (int)hc;                                            \
        const float lh = hc - (float)h0;                                     \
        const float f  = hv ? 1.0f : 0.0f;                                   \
        const float d0 = (1.0f - lh) * f, d1 = lh * f;                       \
        if ((i) == 0) {                                                      \
            rbase = h0; R0 += d0; R1 += d1;                                  \
        } else {                                                             \
            const int s = h0 - rbase; /* 0..4 */                             \
            R0 += (s == 0) ? d0 : 0.0f;                                      \
            R1 += (s == 1) ? d0 : 0.0f; R1 += (s == 0) ? d1 : 0.0f;          \
            R2 += (s == 2) ? d0 : 0.0f; R2 += (s == 1) ? d1 : 0.0f;          \
            R3 += (s == 3) ? d0 : 0.0f; R3 += (s == 2) ? d1 : 0.0f;          \
            R4 += (s == 4) ? d0 : 0.0f; R4 += (s == 3) ? d1 : 0.0f;          \
            R5 += (s == 4) ? d1 : 0.0f;                                      \
        }                                                                    \
    }

#define MKC(j)                                                                \
    {                                                                         \
        const float w  = w_##j;                                              \
        const int   wv = (w >= -0.5f) && (w <= (float)W_IN - 0.5f);          \
        nw += wv;                                                            \
        const float wc = fminf(fmaxf(w, 0.0f), (float)W_IN - 1.0f);          \
        const int   w0 = (int)wc;                                            \
        const float lw = wc - (float)w0;                                     \
        const float f  = wv ? 1.0f : 0.0f;                                   \
        const float d0 = (1.0f - lw) * f, d1 = lw * f;                       \
        if ((j) == 0) {                                                      \
            cbase = w0; C0 += d0; C1 += d1;                                  \
        } else {                                                             \
            const int s = w0 - cbase;                                        \
            C0 += (s == 0) ? d0 : 0.0f;                                      \
            C1 += (s == 1) ? d0 : 0.0f; C1 += (s == 0) ? d1 : 0.0f;          \
            C2 += (s == 2) ? d0 : 0.0f; C2 += (s == 1) ? d1 : 0.0f;          \
            C3 += (s == 3) ? d0 : 0.0f; C3 += (s == 2) ? d1 : 0.0f;          \
            C4 += (s == 4) ? d0 : 0.0f; C4 += (s == 3) ? d1 : 0.0f;          \
            C5 += (s == 4) ? d1 : 0.0f;                                      \
        }                                                                    \
    }

#define GROW(r)                                                               \
    if (R##r != 0.0f) {                                                       \
        const float2* rp = d2 +                                               \
            (size_t)((pixbase + min(rbase + (r), H_IN - 1) * W_IN) *          \
                     (C_CH / 2)) + lane;                                      \
        const float2 v0 = rp[co0], v1 = rp[co1], v2 = rp[co2];                \
        const float2 v3 = rp[co3], v4 = rp[co4], v5 = rp[co5];                \
        const float sx = C0 * v0.x + C1 * v1.x + C2 * v2.x +                  \
                         C3 * v3.x + C4 * v4.x + C5 * v5.x;                   \
        const float sy = C0 * v0.y + C1 * v1.y + C2 * v2.y +                  \
                         C3 * v3.y + C4 * v4.y + C5 * v5.y;                   \
        ax += R##r * sx; ay += R##r * sy;                                     \
    }

__global__ __launch_bounds__(448) void droi_kernel4(const float2* __restrict__ d2,
                                                    const float* __restrict__ rois,
                                                    const float* __restrict__ offset,
                                                    float* __restrict__ out) {
    __shared__ float lds[C_CH * OUTS];   // [c][pw], 3.5 KB
    const int n    = blockIdx.x;
    const int ph   = blockIdx.y;
    const int pw   = threadIdx.x >> 6;   // wave id == output column
    const int lane = threadIdx.x & 63;

    const int b       = (int)rois[n * 5 + 0];
    const int pixbase = b * HW;

    float h_0, h_1, h_2, h_3, w_0, w_1, w_2, w_3;
    {
#pragma clang fp contract(off)
        const float sw    = rintf(rois[n * 5 + 1]) * 0.0625f - 0.5f;
        const float sh    = rintf(rois[n * 5 + 2]) * 0.0625f - 0.5f;
        const float ew    = (rintf(rois[n * 5 + 3]) + 1.0f) * 0.0625f - 0.5f;
        const float eh    = (rintf(rois[n * 5 + 4]) + 1.0f) * 0.0625f - 0.5f;
        const float roi_w = fmaxf(ew - sw, 0.1f);
        const float roi_h = fmaxf(eh - sh, 0.1f);
        const float bin_w = roi_w / 7.0f;
        const float bin_h = roi_h / 7.0f;
        const float sub_w = bin_w / 4.0f;
        const float sub_h = bin_h / 4.0f;
        // PART_SIZE == OUT_SIZE == 7 -> part_h == ph, part_w == pw.
        const float tx = offset[(n * 2 + 0) * NBINS + ph * OUTS + pw] * 0.1f;
        const float ty = offset[(n * 2 + 1) * NBINS + ph * OUTS + pw] * 0.1f;
        const float wstart = (float)pw * bin_w + sw + tx * roi_w;
        const float hstart = (float)ph * bin_h + sh + ty * roi_h;
        h_0 = hstart;                 w_0 = wstart;
        h_1 = hstart + sub_h;         w_1 = wstart + sub_w;
        h_2 = hstart + 2.0f * sub_h;  w_2 = wstart + 2.0f * sub_w;
        h_3 = hstart + 3.0f * sub_h;  w_3 = wstart + 3.0f * sub_w;
    }

    int   nh = 0, nw = 0, rbase = 0, cbase = 0;
    float R0 = 0.f, R1 = 0.f, R2 = 0.f, R3 = 0.f, R4 = 0.f, R5 = 0.f;
    float C0 = 0.f, C1 = 0.f, C2 = 0.f, C3 = 0.f, C4 = 0.f, C5 = 0.f;
    MKR(0) MKR(1) MKR(2) MKR(3)
    MKC(0) MKC(1) MKC(2) MKC(3)

    const int co0 = min(cbase + 0, W_IN - 1) * (C_CH / 2);
    const int co1 = min(cbase + 1, W_IN - 1) * (C_CH / 2);
    const int co2 = min(cbase + 2, W_IN - 1) * (C_CH / 2);
    const int co3 = min(cbase + 3, W_IN - 1) * (C_CH / 2);
    const int co4 = min(cbase + 4, W_IN - 1) * (C_CH / 2);
    const int co5 = min(cbase + 5, W_IN - 1) * (C_CH / 2);

    float ax = 0.0f, ay = 0.0f;
    GROW(0) GROW(1) GROW(2) GROW(3) GROW(4) GROW(5)

    const int   cnt = nh * nw;
    const float inv = cnt > 0 ? 1.0f / (float)cnt : 0.0f;
    lds[(2 * lane) * OUTS + pw]     = ax * inv;
    lds[(2 * lane + 1) * OUTS + pw] = ay * inv;
    __syncthreads();

    // out[n, c, ph, pw]: 896 floats per block, staged -> semi-coalesced.
    const size_t obase = (size_t)n * (C_CH * NBINS) + (size_t)ph * OUTS;
    for (int f = threadIdx.x; f < C_CH * OUTS; f += 448) {
        const int c = f / OUTS, k = f - c * OUTS;
        out[obase + (size_t)c * NBINS + k] = lds[f];
    }
}

// ---------------- fallback (no workspace): CHW gather, known-correct ---------
__global__ __launch_bounds__(512) void droi_fallback(const float* __restrict__ data,
                                                     const float* __restrict__ rois,
                                                     const float* __restrict__ offset,
                                                     float* __restrict__ out) {
#pragma clang fp contract(off)
    __shared__ float lds[C_CH * NBINS];
    const int n    = blockIdx.x;
    const int tid  = threadIdx.x;
    const int wave = tid >> 6;
    const int lane = tid & 63;

    const int   b     = (int)rois[n * 5 + 0];
    const float sw    = rintf(rois[n * 5 + 1]) * 0.0625f - 0.5f;
    const float sh    = rintf(rois[n * 5 + 2]) * 0.0625f - 0.5f;
    const float ew    = (rintf(rois[n * 5 + 3]) + 1.0f) * 0.0625f - 0.5f;
    const float eh    = (rintf(rois[n * 5 + 4]) + 1.0f) * 0.0625f - 0.5f;
    const float roi_w = fmaxf(ew - sw, 0.1f);
    const float roi_h = fmaxf(eh - sh, 0.1f);
    const float bin_w = roi_w / 7.0f, bin_h = roi_h / 7.0f;
    const float sub_w = bin_w / 4.0f, sub_h = bin_h / 4.0f;

    for (int bin = wave; bin < NBINS; bin += 8) {
        const int ph = bin / 7;
        const int pw = bin - ph * 7;
        const float tx = offset[((n * 2 + 0) * 7 + ph) * 7 + pw] * 0.1f;
        const float ty = offset[((n * 2 + 1) * 7 + ph) * 7 + pw] * 0.1f;
        const float wstart = (float)pw * bin_w + sw + tx * roi_w;
        const float hstart = (float)ph * bin_h + sh + ty * roi_h;
        float s0 = 0.0f, s1 = 0.0f;
        int   cnt = 0;
        for (int ih = 0; ih < 4; ih++) {
            const float h = hstart + (float)ih * sub_h;
            if (h < -0.5f || h > (float)H_IN - 0.5f) continue;
            for (int iw = 0; iw < 4; iw++) {
                const float w = wstart + (float)iw * sub_w;
                if (w < -0.5f || w > (float)W_IN - 0.5f) continue;
                cnt++;
                const float hc = fminf(fmaxf(h, 0.0f), (float)H_IN - 1.0f);
                const float wc = fminf(fmaxf(w, 0.0f), (float)W_IN - 1.0f);
                const int h0 = (int)floorf(hc), w0 = (int)floorf(wc);
                const int h1 = min(h0 + 1, H_IN - 1), w1 = min(w0 + 1, W_IN - 1);
                const float lh = hc - (float)h0, lw = wc - (float)w0;
                const float w00 = (1.0f - lh) * (1.0f - lw), w01 = (1.0f - lh) * lw;
                const float w10 = lh * (1.0f - lw), w11 = lh * lw;
                const float* pb  = data + (size_t)b * C_CH * HW;
                const int i00 = h0 * W_IN + w0, i01 = h0 * W_IN + w1;
                const int i10 = h1 * W_IN + w0, i11 = h1 * W_IN + w1;
                const float* pc0 = pb + (size_t)lane * HW;
                const float* pc1 = pb + (size_t)(lane + 64) * HW;
                s0 += w00 * pc0[i00] + w01 * pc0[i01] + w10 * pc0[i10] + w11 * pc0[i11];
                s1 += w00 * pc1[i00] + w01 * pc1[i01] + w10 * pc1[i10] + w11 * pc1[i11];
            }
        }
        lds[lane * NBINS + bin]        = cnt > 0 ? s0 / (float)cnt : 0.0f;
        lds[(lane + 64) * NBINS + bin] = cnt > 0 ? s1 / (float)cnt : 0.0f;
    }
    __syncthreads();
    const size_t obase = (size_t)n * (C_CH * NBINS);
    for (int f = tid; f < C_CH * NBINS; f += 512)
        out[obase + f] = lds[f];
}

extern "C" void kernel_launch(void* const* d_in, const int* in_sizes, int n_in,
                              void* d_out, int out_size, void* d_ws, size_t ws_size,
                              hipStream_t stream) {
    const float* data   = (const float*)d_in[0];
    const float* rois   = (const float*)d_in[1];
    const float* offset = (const float*)d_in[2];
    float*       outp   = (float*)d_out;

    const int N = in_sizes[1] / 5;                 // 512
    const int B = in_sizes[0] / (C_CH * HW);       // 2
    const size_t need = (size_t)B * HW * C_CH * sizeof(float);

    if (ws_size >= need) {
        dim3 gt(HW / 32, C_CH / 32, B), bt(32, 8);
        transpose_kernel<<<gt, bt, 0, stream>>>(data, (float*)d_ws);
        dim3 gd(N, OUTS);
        droi_kernel4<<<gd, 448, 0, stream>>>((const float2*)d_ws, rois, offset, outp);
    } else {
        droi_fallback<<<N, 512, 0, stream>>>(data, rois, offset, outp);
    }
}

// Round 5
// 38.444 us; speedup vs baseline: 5.5538x; 1.0251x over previous
//
#include <hip/hip_runtime.h>

#define C_CH 128
#define H_IN 80
#define W_IN 80
#define HW 6400
#define OUTS 7
#define NBINS 49   // 7x7

// ---------------- transpose (B,C,H,W) -> (B,H,W,C), float4 both sides -------
// Tile: 32 channels x 64 spatial. Loads dwordx4 along spatial (coalesced),
// stores dwordx4 along channel (each wave writes 1024 contiguous bytes).
__global__ __launch_bounds__(256) void transpose4_kernel(const float* __restrict__ in,
                                                         float* __restrict__ out) {
    __shared__ float tile[64][33];
    const int b  = blockIdx.z;
    const int c0 = blockIdx.y * 32;
    const int s0 = blockIdx.x * 64;
    const int t  = threadIdx.x;
#pragma unroll
    for (int i = 0; i < 2; i++) {
        const int c  = i * 16 + (t >> 4);
        const int sB = (t & 15) * 4;
        const float4 v = *(const float4*)&in[(size_t)(b * C_CH + c0 + c) * HW + s0 + sB];
        tile[sB + 0][c] = v.x;
        tile[sB + 1][c] = v.y;
        tile[sB + 2][c] = v.z;
        tile[sB + 3][c] = v.w;
    }
    __syncthreads();
#pragma unroll
    for (int i = 0; i < 2; i++) {
        const int s  = i * 32 + (t >> 3);
        const int cq = (t & 7) * 4;
        float4 o;
        o.x = tile[s][cq + 0];
        o.y = tile[s][cq + 1];
        o.z = tile[s][cq + 2];
        o.w = tile[s][cq + 3];
        *(float4*)&out[(size_t)(b * HW + s0 + s) * C_CH + c0 + cq] = o;
    }
}

// ---------------- main deformable RoI pool (NHWC, rank-1, f4 pair gather) ---
// Grid (N, 7), block 448 = 7 waves, wave == pw (one bin per wave).
// Rank-1 weights: W(r,c) = R_r * C_c over a <=6x6 pixel window (see R4).
// Lane split: half = lane>>5 selects window-column parity, cq = lane&31 the
// channel quad. One dwordx4 wave-load covers 2 adjacent pixels x 128 ch.
// Wave-uniform skips: rows with R_r==0, column pairs with zero weight.
// Cross-half __shfl_xor(32) reduction at the end; lanes 0-31 stage to LDS.

#define MKR(i)                                                                \
    {                                                                         \
        const float h  = h_##i;                                              \
        const int   hv = (h >= -0.5f) && (h <= (float)H_IN - 0.5f);          \
        nh += hv;                                                            \
        const float hc = fminf(fmaxf(h, 0.0f), (float)H_IN - 1.0f);          \
        const int   h0 = (int)hc;                                            \
        const float lh = hc - (float)h0;                                     \
        const float f  = hv ? 1.0f : 0.0f;                                   \
        const float d0 = (1.0f - lh) * f, d1 = lh * f;                       \
        if ((i) == 0) {                                                      \
            rbase = h0; R0 += d0; R1 += d1;                                  \
        } else {                                                             \
            const int s = h0 - rbase; /* 0..4 */                             \
            R0 += (s == 0) ? d0 : 0.0f;                                      \
            R1 += (s == 1) ? d0 : 0.0f; R1 += (s == 0) ? d1 : 0.0f;          \
            R2 += (s == 2) ? d0 : 0.0f; R2 += (s == 1) ? d1 : 0.0f;          \
            R3 += (s == 3) ? d0 : 0.0f; R3 += (s == 2) ? d1 : 0.0f;          \
            R4 += (s == 4) ? d0 : 0.0f; R4 += (s == 3) ? d1 : 0.0f;          \
            R5 += (s == 4) ? d1 : 0.0f;                                      \
        }                                                                    \
    }

#define MKC(j)                                                                \
    {                                                                         \
        const float w  = w_##j;                                              \
        const int   wv = (w >= -0.5f) && (w <= (float)W_IN - 0.5f);          \
        nw += wv;                                                            \
        const float wc = fminf(fmaxf(w, 0.0f), (float)W_IN - 1.0f);          \
        const int   w0 = (int)wc;                                            \
        const float lw = wc - (float)w0;                                     \
        const float f  = wv ? 1.0f : 0.0f;                                   \
        const float d0 = (1.0f - lw) * f, d1 = lw * f;                       \
        if ((j) == 0) {                                                      \
            cbase = w0; C0 += d0; C1 += d1;                                  \
        } else {                                                             \
            const int s = w0 - cbase;                                        \
            C0 += (s == 0) ? d0 : 0.0f;                                      \
            C1 += (s == 1) ? d0 : 0.0f; C1 += (s == 0) ? d1 : 0.0f;          \
            C2 += (s == 2) ? d0 : 0.0f; C2 += (s == 1) ? d1 : 0.0f;          \
            C3 += (s == 3) ? d0 : 0.0f; C3 += (s == 2) ? d1 : 0.0f;          \
            C4 += (s == 4) ? d0 : 0.0f; C4 += (s == 3) ? d1 : 0.0f;          \
            C5 += (s == 4) ? d1 : 0.0f;                                      \
        }                                                                    \
    }

#define GR(r)                                                                 \
    if (R##r != 0.0f) {                                                       \
        const size_t ro =                                                     \
            (size_t)(pixbase + min(rbase + (r), H_IN - 1) * W_IN) * 32;       \
        {                                                                     \
            const float4 v = d4[ro + coff0];                                  \
            const float  g = R##r * ws0;                                      \
            a0 += g * v.x; a1 += g * v.y; a2 += g * v.z; a3 += g * v.w;       \
        }                                                                     \
        if (p1) {                                                             \
            const float4 v = d4[ro + coff1];                                  \
            const float  g = R##r * ws1;                                      \
            a0 += g * v.x; a1 += g * v.y; a2 += g * v.z; a3 += g * v.w;       \
        }                                                                     \
        if (p2) {                                                             \
            const float4 v = d4[ro + coff2];                                  \
            const float  g = R##r * ws2;                                      \
            a0 += g * v.x; a1 += g * v.y; a2 += g * v.z; a3 += g * v.w;       \
        }                                                                     \
    }

__global__ __launch_bounds__(448) void droi_kernel5(const float4* __restrict__ d4,
                                                    const float* __restrict__ rois,
                                                    const float* __restrict__ offset,
                                                    float* __restrict__ out) {
    __shared__ float lds[C_CH * OUTS];   // [c][pw], 3.5 KB
    const int n    = blockIdx.x;
    const int ph   = blockIdx.y;
    const int pw   = threadIdx.x >> 6;   // wave id == output column
    const int lane = threadIdx.x & 63;

    const int b       = (int)rois[n * 5 + 0];
    const int pixbase = b * HW;

    float h_0, h_1, h_2, h_3, w_0, w_1, w_2, w_3;
    {
#pragma clang fp contract(off)
        const float sw    = rintf(rois[n * 5 + 1]) * 0.0625f - 0.5f;
        const float sh    = rintf(rois[n * 5 + 2]) * 0.0625f - 0.5f;
        const float ew    = (rintf(rois[n * 5 + 3]) + 1.0f) * 0.0625f - 0.5f;
        const float eh    = (rintf(rois[n * 5 + 4]) + 1.0f) * 0.0625f - 0.5f;
        const float roi_w = fmaxf(ew - sw, 0.1f);
        const float roi_h = fmaxf(eh - sh, 0.1f);
        const float bin_w = roi_w / 7.0f;
        const float bin_h = roi_h / 7.0f;
        const float sub_w = bin_w / 4.0f;
        const float sub_h = bin_h / 4.0f;
        // PART_SIZE == OUT_SIZE == 7 -> part_h == ph, part_w == pw.
        const float tx = offset[(n * 2 + 0) * NBINS + ph * OUTS + pw] * 0.1f;
        const float ty = offset[(n * 2 + 1) * NBINS + ph * OUTS + pw] * 0.1f;
        const float wstart = (float)pw * bin_w + sw + tx * roi_w;
        const float hstart = (float)ph * bin_h + sh + ty * roi_h;
        h_0 = hstart;                 w_0 = wstart;
        h_1 = hstart + sub_h;         w_1 = wstart + sub_w;
        h_2 = hstart + 2.0f * sub_h;  w_2 = wstart + 2.0f * sub_w;
        h_3 = hstart + 3.0f * sub_h;  w_3 = wstart + 3.0f * sub_w;
    }

    int   nh = 0, nw = 0, rbase = 0, cbase = 0;
    float R0 = 0.f, R1 = 0.f, R2 = 0.f, R3 = 0.f, R4 = 0.f, R5 = 0.f;
    float C0 = 0.f, C1 = 0.f, C2 = 0.f, C3 = 0.f, C4 = 0.f, C5 = 0.f;
    MKR(0) MKR(1) MKR(2) MKR(3)
    MKC(0) MKC(1) MKC(2) MKC(3)

    const int half = lane >> 5;        // window-column parity for this lane
    const int cq   = lane & 31;        // channel quad (4 channels)
    const int coff0 = min(cbase + 0 + half, W_IN - 1) * 32 + cq;
    const int coff1 = min(cbase + 2 + half, W_IN - 1) * 32 + cq;
    const int coff2 = min(cbase + 4 + half, W_IN - 1) * 32 + cq;
    const float ws0 = half ? C1 : C0;
    const float ws1 = half ? C3 : C2;
    const float ws2 = half ? C5 : C4;
    const bool  p1  = (C2 + C3) > 0.0f;   // weights are >= 0
    const bool  p2  = (C4 + C5) > 0.0f;

    float a0 = 0.f, a1 = 0.f, a2 = 0.f, a3 = 0.f;
    GR(0) GR(1) GR(2) GR(3) GR(4) GR(5)

    // fold the two column-parity halves together
    a0 += __shfl_xor(a0, 32, 64);
    a1 += __shfl_xor(a1, 32, 64);
    a2 += __shfl_xor(a2, 32, 64);
    a3 += __shfl_xor(a3, 32, 64);

    const int   cnt = nh * nw;
    const float inv = cnt > 0 ? 1.0f / (float)cnt : 0.0f;
    if (lane < 32) {
        const int c = 4 * cq;
        lds[(c + 0) * OUTS + pw] = a0 * inv;
        lds[(c + 1) * OUTS + pw] = a1 * inv;
        lds[(c + 2) * OUTS + pw] = a2 * inv;
        lds[(c + 3) * OUTS + pw] = a3 * inv;
    }
    __syncthreads();

    // out[n, c, ph, pw]: 896 floats per block, staged -> semi-coalesced.
    const size_t obase = (size_t)n * (C_CH * NBINS) + (size_t)ph * OUTS;
    for (int f = threadIdx.x; f < C_CH * OUTS; f += 448) {
        const int c = f / OUTS, k = f - c * OUTS;
        out[obase + (size_t)c * NBINS + k] = lds[f];
    }
}

// ---------------- fallback (no workspace): CHW gather, known-correct ---------
__global__ __launch_bounds__(512) void droi_fallback(const float* __restrict__ data,
                                                     const float* __restrict__ rois,
                                                     const float* __restrict__ offset,
                                                     float* __restrict__ out) {
#pragma clang fp contract(off)
    __shared__ float lds[C_CH * NBINS];
    const int n    = blockIdx.x;
    const int tid  = threadIdx.x;
    const int wave = tid >> 6;
    const int lane = tid & 63;

    const int   b     = (int)rois[n * 5 + 0];
    const float sw    = rintf(rois[n * 5 + 1]) * 0.0625f - 0.5f;
    const float sh    = rintf(rois[n * 5 + 2]) * 0.0625f - 0.5f;
    const float ew    = (rintf(rois[n * 5 + 3]) + 1.0f) * 0.0625f - 0.5f;
    const float eh    = (rintf(rois[n * 5 + 4]) + 1.0f) * 0.0625f - 0.5f;
    const float roi_w = fmaxf(ew - sw, 0.1f);
    const float roi_h = fmaxf(eh - sh, 0.1f);
    const float bin_w = roi_w / 7.0f, bin_h = roi_h / 7.0f;
    const float sub_w = bin_w / 4.0f, sub_h = bin_h / 4.0f;

    for (int bin = wave; bin < NBINS; bin += 8) {
        const int ph = bin / 7;
        const int pw = bin - ph * 7;
        const float tx = offset[((n * 2 + 0) * 7 + ph) * 7 + pw] * 0.1f;
        const float ty = offset[((n * 2 + 1) * 7 + ph) * 7 + pw] * 0.1f;
        const float wstart = (float)pw * bin_w + sw + tx * roi_w;
        const float hstart = (float)ph * bin_h + sh + ty * roi_h;
        float s0 = 0.0f, s1 = 0.0f;
        int   cnt = 0;
        for (int ih = 0; ih < 4; ih++) {
            const float h = hstart + (float)ih * sub_h;
            if (h < -0.5f || h > (float)H_IN - 0.5f) continue;
            for (int iw = 0; iw < 4; iw++) {
                const float w = wstart + (float)iw * sub_w;
                if (w < -0.5f || w > (float)W_IN - 0.5f) continue;
                cnt++;
                const float hc = fminf(fmaxf(h, 0.0f), (float)H_IN - 1.0f);
                const float wc = fminf(fmaxf(w, 0.0f), (float)W_IN - 1.0f);
                const int h0 = (int)floorf(hc), w0 = (int)floorf(wc);
                const int h1 = min(h0 + 1, H_IN - 1), w1 = min(w0 + 1, W_IN - 1);
                const float lh = hc - (float)h0, lw = wc - (float)w0;
                const float w00 = (1.0f - lh) * (1.0f - lw), w01 = (1.0f - lh) * lw;
                const float w10 = lh * (1.0f - lw), w11 = lh * lw;
                const float* pb  = data + (size_t)b * C_CH * HW;
                const int i00 = h0 * W_IN + w0, i01 = h0 * W_IN + w1;
                const int i10 = h1 * W_IN + w0, i11 = h1 * W_IN + w1;
                const float* pc0 = pb + (size_t)lane * HW;
                const float* pc1 = pb + (size_t)(lane + 64) * HW;
                s0 += w00 * pc0[i00] + w01 * pc0[i01] + w10 * pc0[i10] + w11 * pc0[i11];
                s1 += w00 * pc1[i00] + w01 * pc1[i01] + w10 * pc1[i10] + w11 * pc1[i11];
            }
        }
        lds[lane * NBINS + bin]        = cnt > 0 ? s0 / (float)cnt : 0.0f;
        lds[(lane + 64) * NBINS + bin] = cnt > 0 ? s1 / (float)cnt : 0.0f;
    }
    __syncthreads();
    const size_t obase = (size_t)n * (C_CH * NBINS);
    for (int f = tid; f < C_CH * NBINS; f += 512)
        out[obase + f] = lds[f];
}

extern "C" void kernel_launch(void* const* d_in, const int* in_sizes, int n_in,
                              void* d_out, int out_size, void* d_ws, size_t ws_size,
                              hipStream_t stream) {
    const float* data   = (const float*)d_in[0];
    const float* rois   = (const float*)d_in[1];
    const float* offset = (const float*)d_in[2];
    float*       outp   = (float*)d_out;

    const int N = in_sizes[1] / 5;                 // 512
    const int B = in_sizes[0] / (C_CH * HW);       // 2
    const size_t need = (size_t)B * HW * C_CH * sizeof(float);

    if (ws_size >= need) {
        dim3 gt(HW / 64, C_CH / 32, B), bt(256);
        transpose4_kernel<<<gt, bt, 0, stream>>>(data, (float*)d_ws);
        dim3 gd(N, OUTS);
        droi_kernel5<<<gd, 448, 0, stream>>>((const float4*)d_ws, rois, offset, outp);
    } else {
        droi_fallback<<<N, 512, 0, stream>>>(data, rois, offset, outp);
    }
}